// Round 2
// baseline (557.299 us; speedup 1.0000x reference)
//
#include <hip/hip_runtime.h>
#include <hip/hip_bf16.h>

#define M_TOTAL 65536
#define N_TOTAL 1024
#define K_TOTAL 1024
#define BM 128
#define BN 128
#define BK 32
#define LDK 40              // padded LDS K-stride (bf16): 80B rows, <=2-way conflicts
#define NT (K_TOTAL / BK)   // 32 K-steps

typedef __attribute__((ext_vector_type(8))) short short8;
typedef __attribute__((ext_vector_type(4))) float f32x4;

__device__ __forceinline__ unsigned int fbits(float f) {
    union { float f; unsigned int u; } c; c.f = f; return c.u;
}

// pack hi16(lo), hi16(hi) -> one dword (exact: integer-valued f32, |v|<=256)
__device__ __forceinline__ unsigned int pkhi(float lo, float hi) {
    return __builtin_amdgcn_perm(fbits(hi), fbits(lo), 0x07060302u);
}

// ---- W pre-convert: Wq [N][K] f32 -> Wb tiles [bnb(8)][kt(32)][128][32] bf16 ----
__global__ void wconv(const float* __restrict__ Wq, ushort* __restrict__ Wb) {
    const int n  = blockIdx.x;            // 0..1023 (W row = output channel)
    const int c4 = threadIdx.x * 4;       // 0..1020 (k column)
    float4 v = *(const float4*)(Wq + (size_t)n * K_TOTAL + c4);
    unsigned int lo = pkhi(v.x, v.y);
    unsigned int hi = pkhi(v.z, v.w);
    const int bnb = n >> 7, r = n & 127, kt = c4 >> 5, c = c4 & 31;
    ushort* dst = Wb + ((((size_t)bnb * 32 + kt) * 128 + r) * 32 + c);
    *(uint2*)dst = make_uint2(lo, hi);
}

// ---- main GEMM: 128x128 tile, BK=32, 2-deep register prefetch, dbuf LDS ----
__global__ __launch_bounds__(256, 2)
void qlinear_gemm(const float* __restrict__ X,      // [M,K] x_hat (f32)
                  const float* __restrict__ SXp,    // scalar s_x
                  const ushort* __restrict__ Wb,    // pre-converted bf16 W tiles
                  const float* __restrict__ SW,     // [N] s_w
                  const float* __restrict__ Bq,     // [N] b_int8 (f32 ints)
                  float* __restrict__ Out)          // [M,N] a_hat
{
    __shared__ ushort As[2][BM][LDK];
    __shared__ ushort Bs[2][BN][LDK];

    const int tid = threadIdx.x;

    // XCD-aware remap: xcd = d%8 (round-robin dispatch). Each XCD owns a
    // contiguous range of 64 bm-blocks; the 8 bn-sharers of one X-tile are
    // consecutive on the SAME XCD -> X tile hits that XCD's L2 7/8 times.
    const int d   = blockIdx.x;
    const int xcd = d & 7;
    const int s   = d >> 3;               // 0..511
    const int bm0 = (xcd * 64 + (s >> 3)) * BM;
    const int bnb = s & 7;
    const int bn0 = bnb * BN;

    const float sx = SXp[0];
    const float inv_sx = 1.0f / sx;

    // staging map: thread t -> row t>>1, k-half (t&1)*16
    const int sr = tid >> 1;
    const int sh = (tid & 1) << 4;

    const float*  xg = X  + (size_t)(bm0 + sr) * K_TOTAL + sh;
    const ushort* wg = Wb + (size_t)bnb * 32 * 128 * 32 + sr * 32 + sh;

    const int lane = tid & 63;
    const int wid  = tid >> 6;
    const int wm   = (wid >> 1) << 6;
    const int wn   = (wid & 1) << 6;
    const int fr   = lane & 15;
    const int fg   = lane >> 4;

    f32x4 acc[4][4] = {};

    // two named register sets (static indexing only — no runtime-indexed arrays)
    float4 x0[4], x1[4];
    uint4  w0[2], w1[2];

    auto loadX = [&](int kt, float4* xr) {
        const float4* p = (const float4*)(xg + kt * BK);
        xr[0] = p[0]; xr[1] = p[1]; xr[2] = p[2]; xr[3] = p[3];
    };
    auto loadW = [&](int kt, uint4* wr) {
        const uint4* p = (const uint4*)(wg + (size_t)kt * (128 * 32));
        wr[0] = p[0]; wr[1] = p[1];
    };
    auto store_ = [&](int buf, const float4* xr, const uint4* wr) {
        unsigned int ux[8];
        #pragma unroll
        for (int q = 0; q < 4; ++q) {
            float4 v = xr[q];
            ux[q*2+0] = pkhi(rintf(v.x * inv_sx), rintf(v.y * inv_sx));
            ux[q*2+1] = pkhi(rintf(v.z * inv_sx), rintf(v.w * inv_sx));
        }
        uint4* pa = (uint4*)&As[buf][sr][sh];
        pa[0] = make_uint4(ux[0], ux[1], ux[2], ux[3]);
        pa[1] = make_uint4(ux[4], ux[5], ux[6], ux[7]);
        uint4* pb = (uint4*)&Bs[buf][sr][sh];
        pb[0] = wr[0]; pb[1] = wr[1];
    };
    auto compute = [&](int buf) {
        short8 a[4], b[4];
        #pragma unroll
        for (int i = 0; i < 4; ++i)
            a[i] = *(const short8*)&As[buf][wm + i*16 + fr][fg*8];
        #pragma unroll
        for (int j = 0; j < 4; ++j)
            b[j] = *(const short8*)&Bs[buf][wn + j*16 + fr][fg*8];
        #pragma unroll
        for (int i = 0; i < 4; ++i)
            #pragma unroll
            for (int j = 0; j < 4; ++j)
                acc[i][j] = __builtin_amdgcn_mfma_f32_16x16x32_bf16(
                    a[i], b[j], acc[i][j], 0, 0, 0);
    };

    // prologue: issue tiles 0 and 1, stage tile 0
    loadX(0, x0); loadW(0, w0);
    loadX(1, x1); loadW(1, w1);
    store_(0, x0, w0);
    __syncthreads();

    // main loop, unrolled x2 so register sets are statically named.
    // Invariant at even step kt: lds[0]=tile kt, {x1,w1}=tile kt+1 (in flight
    // since one full iteration ago), {x0,w0} free.
    for (int kt = 0; kt < NT; kt += 2) {
        if (kt + 2 < NT) { loadX(kt + 2, x0); loadW(kt + 2, w0); }
        compute(0);                        // tile kt
        __syncthreads();                   // everyone done reading lds[1] (prev)
        store_(1, x1, w1);                 // tile kt+1 (loads long complete)
        __syncthreads();

        if (kt + 3 < NT) { loadX(kt + 3, x1); loadW(kt + 3, w1); }
        compute(1);                        // tile kt+1
        if (kt + 2 < NT) {
            __syncthreads();
            store_(0, x0, w0);             // tile kt+2
            __syncthreads();
        }
    }

    // epilogue: (acc + round(b_int8/s_x)) * (s_w * s_x)
    // C/D layout: col = lane&15, row = (lane>>4)*4 + reg
    #pragma unroll
    for (int j = 0; j < 4; ++j) {
        const int col = bn0 + wn + j*16 + fr;
        const float sa  = SW[col] * sx;
        const float b32 = rintf(Bq[col] * inv_sx);
        #pragma unroll
        for (int i = 0; i < 4; ++i) {
            const int row0 = bm0 + wm + i*16 + fg*4;
            #pragma unroll
            for (int r = 0; r < 4; ++r) {
                Out[(size_t)(row0 + r) * N_TOTAL + col] = (acc[i][j][r] + b32) * sa;
            }
        }
    }
}

__global__ void sa_tail(const float* __restrict__ SW, const float* __restrict__ SXp,
                        float* __restrict__ Out)
{
    int o = blockIdx.x * blockDim.x + threadIdx.x;
    if (o < N_TOTAL) Out[(size_t)M_TOTAL * N_TOTAL + o] = SW[o] * SXp[0];
}

extern "C" void kernel_launch(void* const* d_in, const int* in_sizes, int n_in,
                              void* d_out, int out_size, void* d_ws, size_t ws_size,
                              hipStream_t stream)
{
    const float* x  = (const float*)d_in[0];
    const float* sx = (const float*)d_in[1];
    const float* wq = (const float*)d_in[2];
    const float* sw = (const float*)d_in[3];
    const float* bq = (const float*)d_in[4];
    float* out   = (float*)d_out;
    ushort* wbuf = (ushort*)d_ws;          // needs 1024*1024*2 = 2 MiB scratch

    wconv<<<1024, 256, 0, stream>>>(wq, wbuf);
    qlinear_gemm<<<(M_TOTAL / BM) * (N_TOTAL / BN), 256, 0, stream>>>(
        x, sx, wbuf, sw, bq, out);
    sa_tail<<<4, 256, 0, stream>>>(sw, sx, out);
}

// Round 3
// 303.760 us; speedup vs baseline: 1.8347x; 1.8347x over previous
//
#include <hip/hip_runtime.h>
#include <hip/hip_bf16.h>

#define M_TOTAL 65536
#define N_TOTAL 1024
#define K_TOTAL 1024
#define BM 256
#define BN 256
#define BK 64
#define NT (K_TOTAL / BK)     // 16 K-tiles
#define NBN (N_TOTAL / BN)    // 4
#define NBM (M_TOTAL / BM)    // 256

typedef __attribute__((ext_vector_type(8))) short short8;
typedef __attribute__((ext_vector_type(4))) float f32x4;

static __device__ __forceinline__ unsigned fbits(float f) {
    union { float f; unsigned u; } c; c.f = f; return c.u;
}
// pack hi16(lo),hi16(hi) -> dword (exact: integer-valued f32, |v| <= 256)
static __device__ __forceinline__ unsigned pkhi(float lo, float hi) {
    return __builtin_amdgcn_perm(fbits(hi), fbits(lo), 0x07060302u);
}
// byte offset of (row, 16B-slot) inside a [256][64]-ushort tile, T2 XOR swizzle
static __device__ __forceinline__ int swz(int row, int slot) {
    return row * 128 + ((slot ^ (row & 7)) << 4);
}

// ---- W pre-convert: Wq [1024][1024] f32 -> Wb bf16 tiles [bnb(4)][kt(16)][256][64]
__global__ void wconv(const float* __restrict__ Wq, ushort* __restrict__ Wb) {
    const int n = blockIdx.x, c4 = threadIdx.x * 4;
    float4 v = *(const float4*)(Wq + (size_t)n * K_TOTAL + c4);
    const int bnb = n >> 8, row = n & 255, kt = c4 >> 6, col = c4 & 63;
    *(uint2*)(Wb + (((size_t)(bnb * NT + kt) * 256 + row) * 64 + col)) =
        make_uint2(pkhi(v.x, v.y), pkhi(v.z, v.w));
}

// ---- main GEMM: 256x256 tile, BK=64, 8 waves, 4-phase schedule ----
__global__ __launch_bounds__(512, 2)
void qgemm(const float* __restrict__ X, const float* __restrict__ SXp,
           const ushort* __restrict__ Wb, const float* __restrict__ SW,
           const float* __restrict__ Bq, float* __restrict__ Out)
{
    __shared__ ushort As[2][256][64];   // 64 KiB (A: X rows)
    __shared__ ushort Bs[2][256][64];   // 64 KiB (B: W rows)
    char* const abase = (char*)&As[0][0][0];
    char* const bbase = (char*)&Bs[0][0][0];

    const int tid = threadIdx.x;

    // XCD-bijective remap (nwg=1024 % 8 == 0): each XCD owns 32 bm-panels,
    // bn fastest -> the 4 bn-sharers of an X panel are consecutive on one XCD.
    const int d = blockIdx.x;
    const int g = (d & 7) * 128 + (d >> 3);
    const int bn_idx = g & 3, bm_idx = g >> 2;
    const int bm0 = bm_idx * BM, bn0 = bn_idx * BN;

    const float sx = SXp[0], inv_sx = 1.0f / sx;

    // staging maps
    const int ar  = tid >> 2;            // A row (within half), + h*128
    const int ac  = (tid & 3) << 4;      // A col base (f32 elems)
    const int asb = (tid & 3) << 1;      // A 16B-slot base
    const int br_ = tid >> 1;            // B row
    const int bsb = (tid & 1) << 2;      // B 16B-slot base

    const float*  xrow = X  + (size_t)(bm0 + ar) * K_TOTAL + ac;
    const ushort* wpan = Wb + (size_t)bn_idx * NT * 16384 + tid * 32;

    // wave / fragment indices
    const int lane = tid & 63, w = tid >> 6;
    const int wm = (w >> 2) << 7;        // 0 / 128
    const int wn = (w & 3) << 6;         // 0 / 64 / 128 / 192
    const int fr = lane & 15, fg = lane >> 4;

    f32x4 acc[8][4] = {};

    float4 xa0[4], xa1[4];               // staged A halves (f32)
    uint4  wstg[4];                      // staged B (bf16 packed)
    short8 af[4], bf[4];                 // fragments

    auto issueA = [&](int kt, int h, float4* dst) {
        const float4* p = (const float4*)(xrow + (size_t)h * 128 * K_TOTAL + kt * BK);
        dst[0] = p[0]; dst[1] = p[1]; dst[2] = p[2]; dst[3] = p[3];
    };
    auto issueB = [&](int kt) {
        const uint4* p = (const uint4*)(wpan + (size_t)kt * 16384);
        wstg[0] = p[0]; wstg[1] = p[1]; wstg[2] = p[2]; wstg[3] = p[3];
    };
    auto writeA = [&](int buf, int h, const float4* v) {
        unsigned u[8];
        #pragma unroll
        for (int q = 0; q < 4; ++q) {
            u[2*q+0] = pkhi(rintf(v[q].x * inv_sx), rintf(v[q].y * inv_sx));
            u[2*q+1] = pkhi(rintf(v[q].z * inv_sx), rintf(v[q].w * inv_sx));
        }
        const int row = h * 128 + ar;
        char* base = abase + buf * 65536;
        *(uint4*)(base + swz(row, asb + 0)) = make_uint4(u[0], u[1], u[2], u[3]);
        *(uint4*)(base + swz(row, asb + 1)) = make_uint4(u[4], u[5], u[6], u[7]);
    };
    auto writeB = [&](int buf) {
        char* base = bbase + buf * 65536;
        #pragma unroll
        for (int i = 0; i < 4; ++i)
            *(uint4*)(base + swz(br_, bsb + i)) = wstg[i];
    };
    auto readA = [&](int buf, int mh, int kk) {   // mh=0: m0..3, mh=1: m4..7
        char* base = abase + buf * 65536;
        #pragma unroll
        for (int i = 0; i < 4; ++i) {
            const int row = wm + (mh * 4 + i) * 16 + fr;
            af[i] = *(const short8*)(base + swz(row, kk * 4 + fg));
        }
    };
    auto readB = [&](int buf, int kk) {
        char* base = bbase + buf * 65536;
        #pragma unroll
        for (int j = 0; j < 4; ++j) {
            const int row = wn + j * 16 + fr;
            bf[j] = *(const short8*)(base + swz(row, kk * 4 + fg));
        }
    };
    auto mfma16 = [&](int mh) {
        __builtin_amdgcn_s_setprio(1);
        #pragma unroll
        for (int i = 0; i < 4; ++i)
            #pragma unroll
            for (int j = 0; j < 4; ++j)
                acc[mh*4+i][j] = __builtin_amdgcn_mfma_f32_16x16x32_bf16(
                    af[i], bf[j], acc[mh*4+i][j], 0, 0, 0);
        __builtin_amdgcn_s_setprio(0);
    };

    #define SBAR  __builtin_amdgcn_s_barrier()
    #define SCHED __builtin_amdgcn_sched_barrier(0)

    // prologue: stage tile 0 into buf 0
    issueA(0, 0, xa0); issueA(0, 1, xa1); issueB(0);
    writeA(0, 0, xa0); writeA(0, 1, xa1); writeB(0);
    __syncthreads();

    for (int t = 0; t < NT; ++t) {
        const int cur = t & 1, nxt = cur ^ 1;
        const bool pf = (t + 1 < NT);
        // ---- phase 0: kk=0, m0..3 ----
        if (pf) issueA(t + 1, 0, xa0);
        readA(cur, 0, 0); readB(cur, 0);
        SCHED; SBAR;
        mfma16(0);
        SCHED; SBAR;
        // ---- phase 1: kk=0, m4..7 (reuse bf) ----
        if (pf) issueA(t + 1, 1, xa1);
        readA(cur, 1, 0);
        SCHED; SBAR;
        mfma16(1);
        SCHED; SBAR;
        // ---- phase 2: kk=1, m0..3 ----
        if (pf) issueB(t + 1);
        readA(cur, 0, 1); readB(cur, 1);
        SCHED; SBAR;
        mfma16(0);
        SCHED; SBAR;
        // ---- phase 3: kk=1, m4..7 + stage tile t+1 into buf nxt ----
        readA(cur, 1, 1);
        if (pf) { writeA(nxt, 0, xa0); writeA(nxt, 1, xa1); writeB(nxt); }
        SCHED;
        mfma16(1);
        SCHED;
        __syncthreads();   // drains ds_writes (and already-consumed vmem); swaps buffers
    }

    // epilogue: (acc + rint(b_int8/s_x)) * (s_w*s_x); C/D: col=lane&15, row=(lane>>4)*4+r
    #pragma unroll
    for (int n = 0; n < 4; ++n) {
        const int col = bn0 + wn + n * 16 + fr;
        const float sa  = SW[col] * sx;
        const float b32 = rintf(Bq[col] * inv_sx);
        #pragma unroll
        for (int m = 0; m < 8; ++m) {
            const size_t r0 = (size_t)(bm0 + wm + m * 16 + fg * 4) * N_TOTAL + col;
            #pragma unroll
            for (int r = 0; r < 4; ++r)
                Out[r0 + (size_t)r * N_TOTAL] = (acc[m][n][r] + b32) * sa;
        }
    }
    #undef SBAR
    #undef SCHED
}

__global__ void sa_tail(const float* __restrict__ SW, const float* __restrict__ SXp,
                        float* __restrict__ Out)
{
    int o = blockIdx.x * blockDim.x + threadIdx.x;
    if (o < N_TOTAL) Out[(size_t)M_TOTAL * N_TOTAL + o] = SW[o] * SXp[0];
}

extern "C" void kernel_launch(void* const* d_in, const int* in_sizes, int n_in,
                              void* d_out, int out_size, void* d_ws, size_t ws_size,
                              hipStream_t stream)
{
    const float* x  = (const float*)d_in[0];
    const float* sx = (const float*)d_in[1];
    const float* wq = (const float*)d_in[2];
    const float* sw = (const float*)d_in[3];
    const float* bq = (const float*)d_in[4];
    float* out   = (float*)d_out;
    ushort* wbuf = (ushort*)d_ws;   // 2 MiB (proven available in round 2)

    wconv<<<1024, 256, 0, stream>>>(wq, wbuf);
    qgemm<<<NBM * NBN, 512, 0, stream>>>(x, sx, wbuf, sw, bq, out);
    sa_tail<<<4, 256, 0, stream>>>(sw, sx, out);
}

// Round 4
// 277.835 us; speedup vs baseline: 2.0059x; 1.0933x over previous
//
#include <hip/hip_runtime.h>
#include <hip/hip_bf16.h>

#define M_TOTAL 65536
#define N_TOTAL 1024
#define K_TOTAL 1024
#define BM 256
#define BN 256
#define BK 64
#define NT 16

typedef __attribute__((ext_vector_type(8))) short short8;
typedef __attribute__((ext_vector_type(4))) float f32x4;

typedef __attribute__((address_space(3))) void lds_vp;
typedef const __attribute__((address_space(1))) void glb_vp;

static __device__ __forceinline__ unsigned fbits(float f) {
    union { float f; unsigned u; } c; c.f = f; return c.u;
}
// pack hi16(lo),hi16(hi) -> dword (exact: integer-valued f32, |v| <= 256)
static __device__ __forceinline__ unsigned pkhi(float lo, float hi) {
    return __builtin_amdgcn_perm(fbits(hi), fbits(lo), 0x07060302u);
}

// ---- W pre-convert, PRE-SWIZZLED tile-linear layout -------------------------
// Wb = [bnb(4)][kt(16)] tiles of [256 rows][64 cols] bf16, stored so that a
// LINEAR glds fill leaves LDS slot s of row r holding element-slot s^(r&7).
__global__ void wconv(const float* __restrict__ Wq, ushort* __restrict__ Wb) {
    const int n = blockIdx.x, c4 = threadIdx.x * 4;   // 1024 blocks x 256 thr
    float4 v = *(const float4*)(Wq + (size_t)n * K_TOTAL + c4);
    const int bnb = n >> 8, row = n & 255, kt = c4 >> 6, c = c4 & 63;
    const int cs = c ^ ((row & 7) << 3);              // inverse (==) read swizzle
    ushort* dst = Wb + ((size_t)(bnb * NT + kt) * 16384 + row * 64 + cs);
    *(uint2*)dst = make_uint2(pkhi(v.x, v.y), pkhi(v.z, v.w));
}

// ---- main GEMM: 256x256, BK=64, 8 waves, 4-phase, glds-B + reg-staged A ----
__global__ __launch_bounds__(512, 2)
void qgemm(const float* __restrict__ X, const float* __restrict__ SXp,
           const ushort* __restrict__ Wb, const float* __restrict__ SW,
           const float* __restrict__ Bq, float* __restrict__ Out)
{
    __shared__ uint4 smem4[8192];          // 128 KiB: A tiles @0, B tiles @64KiB
    char* const smem = (char*)smem4;

    const int tid = threadIdx.x;

    // XCD-bijective remap: 4 bn-sharers of an X panel consecutive on one XCD
    const int d = blockIdx.x;
    const int g = (d & 7) * 128 + (d >> 3);
    const int bn_idx = g & 3, bm_idx = g >> 2;
    const int bm0 = bm_idx * BM, bn0 = bn_idx * BN;

    const float sx = SXp[0], inv_sx = 1.0f / sx;

    // A staging: thread -> row ar (+h*128), 16 f32 at col (tid&3)*16
    const int ar = tid >> 2;
    const int ac = (tid & 3) << 4;
    const float* xg = X + (size_t)(bm0 + ar) * K_TOTAL + ac;
    const int awslot = (tid & 3) << 1;                  // 2 slots per thread
    const int awsw0 = ((awslot    ) ^ (ar & 7)) << 4;   // swizzled byte offs
    const int awsw1 = ((awslot + 1) ^ (ar & 7)) << 4;

    // wave / fragment indices
    const int lane = tid & 63, w = tid >> 6;
    const int wm = (w >> 2) << 7, wn = (w & 3) << 6;
    const int fr = lane & 15, fg = lane >> 4;
    const int s0 = ((fg    ) ^ (fr & 7)) << 4;          // kk=0 slot byte
    const int s1 = ((fg + 4) ^ (fr & 7)) << 4;          // kk=1 slot byte
    const int arow = (wm + fr) * 128;                   // A-tile row byte base
    const int brow = (wn + fr) * 128;                   // B-tile row byte base

    // B glds source: wave w fills rows w*32..w*32+31 (4 x 1024B instrs)
    const char* wsrc = (const char*)Wb + (size_t)bn_idx * NT * 32768
                     + w * 4096 + lane * 16;

    f32x4 acc[8][4] = {};
    float4 xh0[4], xh1[4];
    short8 af[4], bf[4];

    auto issueA = [&](int kt, int h, float4* dst) {
        const float4* p = (const float4*)(xg + (size_t)h * 128 * K_TOTAL + kt * BK);
        dst[0] = p[0]; dst[1] = p[1]; dst[2] = p[2]; dst[3] = p[3];
    };
    auto packA = [&](int buf, int h, const float4* v) {
        unsigned u[8];
        #pragma unroll
        for (int q = 0; q < 4; ++q) {
            u[2*q+0] = pkhi(rintf(v[q].x * inv_sx), rintf(v[q].y * inv_sx));
            u[2*q+1] = pkhi(rintf(v[q].z * inv_sx), rintf(v[q].w * inv_sx));
        }
        char* base = smem + buf * 32768 + (h * 128 + ar) * 128;
        *(uint4*)(base + awsw0) = make_uint4(u[0], u[1], u[2], u[3]);
        *(uint4*)(base + awsw1) = make_uint4(u[4], u[5], u[6], u[7]);
    };
    auto gldsB = [&](int kt, int buf) {
        const char* src = wsrc + (size_t)kt * 32768;
        char* dst = smem + 65536 + buf * 32768 + w * 4096;
        __builtin_amdgcn_global_load_lds((glb_vp*)(src +    0), (lds_vp*)(dst +    0), 16, 0, 0);
        __builtin_amdgcn_global_load_lds((glb_vp*)(src + 1024), (lds_vp*)(dst + 1024), 16, 0, 0);
        __builtin_amdgcn_global_load_lds((glb_vp*)(src + 2048), (lds_vp*)(dst + 2048), 16, 0, 0);
        __builtin_amdgcn_global_load_lds((glb_vp*)(src + 3072), (lds_vp*)(dst + 3072), 16, 0, 0);
    };
    auto readA = [&](int buf, int mh, int sk) {
        const char* base = smem + buf * 32768 + arow;
        #pragma unroll
        for (int i = 0; i < 4; ++i)
            af[i] = *(const short8*)(base + (mh * 64 + i * 16) * 128 + sk);
    };
    auto readB = [&](int buf, int sk) {
        const char* base = smem + 65536 + buf * 32768 + brow;
        #pragma unroll
        for (int j = 0; j < 4; ++j)
            bf[j] = *(const short8*)(base + (j * 16) * 128 + sk);
    };
    auto mfma16 = [&](int mh) {
        __builtin_amdgcn_s_setprio(1);
        #pragma unroll
        for (int i = 0; i < 4; ++i)
            #pragma unroll
            for (int j = 0; j < 4; ++j)
                acc[mh*4+i][j] = __builtin_amdgcn_mfma_f32_16x16x32_bf16(
                    af[i], bf[j], acc[mh*4+i][j], 0, 0, 0);
        __builtin_amdgcn_s_setprio(0);
    };

    // prologue: stage tile 0 (A reg-staged, B glds); syncthreads drains both
    issueA(0, 0, xh0); issueA(0, 1, xh1);
    gldsB(0, 0);
    packA(0, 0, xh0); packA(0, 1, xh1);
    __syncthreads();

    for (int t = 0; t < NT; ++t) {
        const int cur = t & 1, nxt = cur ^ 1;
        const bool pf = (t + 1 < NT);
        // P0: issue A-h0(t+1); compute (m0-3, k0)
        if (pf) issueA(t + 1, 0, xh0);
        readA(cur, 0, s0); readB(cur, s0);
        __builtin_amdgcn_s_barrier();
        mfma16(0);
        __builtin_amdgcn_s_barrier();
        // P1: issue A-h1(t+1) + B-glds(t+1); compute (m4-7, k0)
        if (pf) { issueA(t + 1, 1, xh1); gldsB(t + 1, nxt); }
        readA(cur, 1, s0);
        __builtin_amdgcn_s_barrier();
        mfma16(1);
        __builtin_amdgcn_s_barrier();
        // P2: pack+write A-h0(t+1); compute (m0-3, k1)
        if (pf) packA(nxt, 0, xh0);
        readA(cur, 0, s1); readB(cur, s1);
        __builtin_amdgcn_s_barrier();
        mfma16(0);
        __builtin_amdgcn_s_barrier();
        // P3: pack+write A-h1(t+1); compute (m4-7, k1); swap
        if (pf) packA(nxt, 1, xh1);
        readA(cur, 1, s1);
        __builtin_amdgcn_s_barrier();
        mfma16(1);
        __syncthreads();   // vmcnt(0)+lgkm(0)+barrier: glds/ds_writes visible
    }

    // epilogue: (acc + rint(b_int8/s_x)) * (s_w*s_x); C/D: col=lane&15, row=(lane>>4)*4+r
    #pragma unroll
    for (int n = 0; n < 4; ++n) {
        const int col = bn0 + wn + n * 16 + fr;
        const float sa  = SW[col] * sx;
        const float b32 = rintf(Bq[col] * inv_sx);
        #pragma unroll
        for (int m = 0; m < 8; ++m) {
            const size_t r0 = (size_t)(bm0 + wm + m * 16 + fg * 4) * N_TOTAL + col;
            #pragma unroll
            for (int r = 0; r < 4; ++r)
                Out[r0 + (size_t)r * N_TOTAL] = (acc[m][n][r] + b32) * sa;
        }
    }
}

__global__ void sa_tail(const float* __restrict__ SW, const float* __restrict__ SXp,
                        float* __restrict__ Out)
{
    int o = blockIdx.x * blockDim.x + threadIdx.x;
    if (o < N_TOTAL) Out[(size_t)M_TOTAL * N_TOTAL + o] = SW[o] * SXp[0];
}

extern "C" void kernel_launch(void* const* d_in, const int* in_sizes, int n_in,
                              void* d_out, int out_size, void* d_ws, size_t ws_size,
                              hipStream_t stream)
{
    const float* x  = (const float*)d_in[0];
    const float* sx = (const float*)d_in[1];
    const float* wq = (const float*)d_in[2];
    const float* sw = (const float*)d_in[3];
    const float* bq = (const float*)d_in[4];
    float* out   = (float*)d_out;
    ushort* wbuf = (ushort*)d_ws;          // 2 MiB scratch

    wconv<<<1024, 256, 0, stream>>>(wq, wbuf);
    qgemm<<<(M_TOTAL / BM) * (N_TOTAL / BN), 512, 0, stream>>>(
        x, sx, wbuf, sw, bq, out);
    sa_tail<<<4, 256, 0, stream>>>(sw, sx, out);
}

// Round 5
// 221.489 us; speedup vs baseline: 2.5162x; 1.2544x over previous
//
#include <hip/hip_runtime.h>
#include <hip/hip_bf16.h>

#define M_TOTAL 65536
#define N_TOTAL 1024
#define K_TOTAL 1024
#define BM 256
#define BN 256
#define BK 64
#define NT 16

typedef __attribute__((ext_vector_type(8))) short short8;
typedef __attribute__((ext_vector_type(4))) float f32x4;

typedef __attribute__((address_space(3))) void lds_vp;
typedef const __attribute__((address_space(1))) void glb_vp;

#define BAR()    asm volatile("s_barrier" ::: "memory")
#define WAITV8() asm volatile("s_waitcnt vmcnt(8)" ::: "memory")
#define WAITV0() asm volatile("s_waitcnt vmcnt(0)" ::: "memory")
#define WAITL0() asm volatile("s_waitcnt lgkmcnt(0)" ::: "memory")

static __device__ __forceinline__ unsigned fbits(float f) {
    union { float f; unsigned u; } c; c.f = f; return c.u;
}
// pack hi16(lo),hi16(hi) -> dword (exact: integer-valued f32, |v| <= 256)
static __device__ __forceinline__ unsigned pkhi(float lo, float hi) {
    return __builtin_amdgcn_perm(fbits(hi), fbits(lo), 0x07060302u);
}

// ---- W pre-convert, PRE-SWIZZLED tile-linear layout -------------------------
// Wb = [bnb(4)][kt(16)] tiles of [256 rows][64 cols] bf16, stored so a LINEAR
// glds fill leaves LDS slot s of row r holding element-slot s^(r&7).
__global__ void wconv(const float* __restrict__ Wq, ushort* __restrict__ Wb) {
    const int n = blockIdx.x, c4 = threadIdx.x * 4;   // 1024 blocks x 256 thr
    float4 v = *(const float4*)(Wq + (size_t)n * K_TOTAL + c4);
    const int bnb = n >> 8, row = n & 255, kt = c4 >> 6, c = c4 & 63;
    const int cs = c ^ ((row & 7) << 3);              // inverse (==) read swizzle
    ushort* dst = Wb + ((size_t)(bnb * NT + kt) * 16384 + row * 64 + cs);
    *(uint2*)dst = make_uint2(pkhi(v.x, v.y), pkhi(v.z, v.w));
}

// ---- main GEMM: 256x256, BK=64, 8 waves, 4-phase, counted-vmcnt schedule ----
__global__ __launch_bounds__(512, 2)
void qgemm(const float* __restrict__ X, const float* __restrict__ SXp,
           const ushort* __restrict__ Wb, const float* __restrict__ SW,
           const float* __restrict__ Bq, float* __restrict__ Out)
{
    __shared__ uint4 smem4[8192];          // 128 KiB: A tiles @0, B tiles @64KiB
    char* const smem = (char*)smem4;

    const int tid = threadIdx.x;

    // XCD-bijective remap: 4 bn-sharers of an X panel consecutive on one XCD
    const int d = blockIdx.x;
    const int g = (d & 7) * 128 + (d >> 3);
    const int bn_idx = g & 3, bm_idx = g >> 2;
    const int bm0 = bm_idx * BM, bn0 = bn_idx * BN;

    const float sx = SXp[0], inv_sx = 1.0f / sx;

    // A staging: thread -> row ar (+h*128), 16 f32 at col (tid&3)*16
    const int ar = tid >> 2;
    const int ac = (tid & 3) << 4;
    const float* xg = X + (size_t)(bm0 + ar) * K_TOTAL + ac;
    const int awslot = (tid & 3) << 1;
    const int awsw0 = ((awslot    ) ^ (ar & 7)) << 4;
    const int awsw1 = ((awslot + 1) ^ (ar & 7)) << 4;

    // wave / fragment indices
    const int lane = tid & 63, w = tid >> 6;
    const int wm = (w >> 2) << 7, wn = (w & 3) << 6;
    const int fr = lane & 15, fg = lane >> 4;
    const int s0 = ((fg    ) ^ (fr & 7)) << 4;
    const int s1 = ((fg + 4) ^ (fr & 7)) << 4;
    const int arow = (wm + fr) * 128;
    const int brow = (wn + fr) * 128;

    // B glds source: wave w fills rows w*32..w*32+31 (4 x 1024B instrs)
    const char* wsrc = (const char*)Wb + (size_t)bn_idx * NT * 32768
                     + w * 4096 + lane * 16;

    f32x4 acc[8][4] = {};
    float4 xh0[4], xh1[4];
    short8 af[4], bf[4];

    auto issueA = [&](int kt, int h, float4* dst) {
        const float4* p = (const float4*)(xg + (size_t)h * 128 * K_TOTAL + kt * BK);
        dst[0] = p[0]; dst[1] = p[1]; dst[2] = p[2]; dst[3] = p[3];
    };
    auto packA = [&](int buf, int h, const float4* v) {
        unsigned u[8];
        #pragma unroll
        for (int q = 0; q < 4; ++q) {
            u[2*q+0] = pkhi(rintf(v[q].x * inv_sx), rintf(v[q].y * inv_sx));
            u[2*q+1] = pkhi(rintf(v[q].z * inv_sx), rintf(v[q].w * inv_sx));
        }
        char* base = smem + buf * 32768 + (h * 128 + ar) * 128;
        *(uint4*)(base + awsw0) = make_uint4(u[0], u[1], u[2], u[3]);
        *(uint4*)(base + awsw1) = make_uint4(u[4], u[5], u[6], u[7]);
    };
    auto gldsB = [&](int kt, int buf) {
        const char* src = wsrc + (size_t)kt * 32768;
        char* dst = smem + 65536 + buf * 32768 + w * 4096;
        __builtin_amdgcn_global_load_lds((glb_vp*)(src +    0), (lds_vp*)(dst +    0), 16, 0, 0);
        __builtin_amdgcn_global_load_lds((glb_vp*)(src + 1024), (lds_vp*)(dst + 1024), 16, 0, 0);
        __builtin_amdgcn_global_load_lds((glb_vp*)(src + 2048), (lds_vp*)(dst + 2048), 16, 0, 0);
        __builtin_amdgcn_global_load_lds((glb_vp*)(src + 3072), (lds_vp*)(dst + 3072), 16, 0, 0);
    };
    auto readA = [&](int buf, int mh, int sk) {
        const char* base = smem + buf * 32768 + arow;
        #pragma unroll
        for (int i = 0; i < 4; ++i)
            af[i] = *(const short8*)(base + (mh * 64 + i * 16) * 128 + sk);
    };
    auto readB = [&](int buf, int sk) {
        const char* base = smem + 65536 + buf * 32768 + brow;
        #pragma unroll
        for (int j = 0; j < 4; ++j)
            bf[j] = *(const short8*)(base + (j * 16) * 128 + sk);
    };
    auto mfma16 = [&](int mh) {
        __builtin_amdgcn_s_setprio(1);
        #pragma unroll
        for (int i = 0; i < 4; ++i)
            #pragma unroll
            for (int j = 0; j < 4; ++j)
                acc[mh*4+i][j] = __builtin_amdgcn_mfma_f32_16x16x32_bf16(
                    af[i], bf[j], acc[mh*4+i][j], 0, 0, 0);
        __builtin_amdgcn_s_setprio(0);
    };

    // ---- prologue: stage tile 0; issue A(1); counted wait for gldsB(0) ----
    issueA(0, 0, xh0); issueA(0, 1, xh1);
    gldsB(0, 0);
    packA(0, 0, xh0); packA(0, 1, xh1);    // reg-dep waits (vmcnt<=4) skip glds
    issueA(1, 0, xh0); issueA(1, 1, xh1);  // A(1), consumed at tile0 P2/P3
    WAITV8();                              // queue [gldsB0 x4, A1 x8] -> glds done
    WAITL0();                              // packA ds_writes visible
    BAR();

    for (int t = 0; t < NT; ++t) {
        const int cur = t & 1, nxt = cur ^ 1;
        const bool pf  = (t + 1 < NT);
        const bool pf2 = (t + 2 < NT);
        // P0: gldsB(t+1) FIRST (oldest in vmem queue); compute (m0-3, k0)
        if (pf) gldsB(t + 1, nxt);
        readA(cur, 0, s0); readB(cur, s0);
        BAR();
        mfma16(0);
        BAR();
        // P1: compute (m4-7, k0)
        readA(cur, 1, s0);
        BAR();
        mfma16(1);
        BAR();
        // P2: pack A(t+1,h0) then immediately re-issue xh0 <- A(t+2,h0)
        if (pf)  packA(nxt, 0, xh0);
        if (pf2) issueA(t + 2, 0, xh0);
        readA(cur, 0, s1); readB(cur, s1);
        BAR();
        mfma16(0);
        BAR();
        // P3: pack A(t+1,h1), re-issue xh1 <- A(t+2,h1); counted tile-end wait
        if (pf)  packA(nxt, 1, xh1);
        if (pf2) issueA(t + 2, 1, xh1);
        readA(cur, 1, s1);
        BAR();
        mfma16(1);
        if (pf) {
            if (pf2) WAITV8();   // retire gldsB(t+1); keep A(t+2) x8 in flight
            else     WAITV0();   // t=14: nothing newer than gldsB(15) in queue
            WAITL0();            // packA ds_writes visible to all waves
            BAR();
        }
    }

    // epilogue: (acc + rint(b_int8/s_x)) * (s_w*s_x); C/D: col=lane&15, row=(lane>>4)*4+r
    #pragma unroll
    for (int n = 0; n < 4; ++n) {
        const int col = bn0 + wn + n * 16 + fr;
        const float sa  = SW[col] * sx;
        const float b32 = rintf(Bq[col] * inv_sx);
        #pragma unroll
        for (int m = 0; m < 8; ++m) {
            const size_t r0 = (size_t)(bm0 + wm + m * 16 + fg * 4) * N_TOTAL + col;
            #pragma unroll
            for (int r = 0; r < 4; ++r)
                Out[r0 + (size_t)r * N_TOTAL] = (acc[m][n][r] + b32) * sa;
        }
    }
}

__global__ void sa_tail(const float* __restrict__ SW, const float* __restrict__ SXp,
                        float* __restrict__ Out)
{
    int o = blockIdx.x * blockDim.x + threadIdx.x;
    if (o < N_TOTAL) Out[(size_t)M_TOTAL * N_TOTAL + o] = SW[o] * SXp[0];
}

extern "C" void kernel_launch(void* const* d_in, const int* in_sizes, int n_in,
                              void* d_out, int out_size, void* d_ws, size_t ws_size,
                              hipStream_t stream)
{
    const float* x  = (const float*)d_in[0];
    const float* sx = (const float*)d_in[1];
    const float* wq = (const float*)d_in[2];
    const float* sw = (const float*)d_in[3];
    const float* bq = (const float*)d_in[4];
    float* out   = (float*)d_out;
    ushort* wbuf = (ushort*)d_ws;          // 2 MiB scratch

    wconv<<<1024, 256, 0, stream>>>(wq, wbuf);
    qgemm<<<(M_TOTAL / BM) * (N_TOTAL / BN), 512, 0, stream>>>(
        x, sx, wbuf, sw, bq, out);
    sa_tail<<<4, 256, 0, stream>>>(sw, sx, out);
}